// Round 13
// baseline (9424.886 us; speedup 1.0000x reference)
//
#include <hip/hip_runtime.h>
#include <hip/hip_bf16.h>
#include <stdint.h>

// LCA on MI355X, round 18. G-form f16 (PASSED r17: 8.10ms, absmax 0.015625).
// r17 decomposition of MODE 3 (~91us): MFMA 27us (floor), LDS-read 39us,
// epilogue HBM 32us -- but only 2 blocks/CU (LDS 64KB, Occ 19%) so the phases
// serialize instead of overlapping. Changes:
//  - MODE 3: TBK 64->32 -> LDS 32KB -> 4 blocks/CU = 16 waves/CU. K-order
//    unchanged (sequential 32-wide slices) -> numerics identical.
//  - CPR=4 fold CORRECTED to (r ^ (r>>2)) & 3: bank position (16r+4f)%32
//    hits each 16B slot exactly 2x per 16-lane phase = 2-way = free (m136).
//    [r11's revert compared r8 NW=4 vs r10 NW=8 -- invalid cross-geometry
//    comparison; plain r&3 is a true 4-way: {0,4,8,12} share a slot.]
//  - MODE 3 epilogue: per-mt gather (32 transient VGPR, not 128) so the
//    kernel fits 128 VGPR at WEU=4 (r17 measured exactly 128).
// ws need 145.9MB (proven available); fallback: residual path (9.39ms).

typedef __bf16 bf16_t;
typedef _Float16 f16_t;
typedef float f32x4 __attribute__((ext_vector_type(4)));
typedef __bf16 bf16x8 __attribute__((ext_vector_type(8)));
typedef _Float16 f16x8 __attribute__((ext_vector_type(8)));
typedef int int4v __attribute__((ext_vector_type(4)));

#define BM 128

template <typename ET>
static __device__ __forceinline__ f32x4 mfma16(int4v a, int4v b, f32x4 c) {
    if constexpr (__is_same(ET, bf16_t))
        return __builtin_amdgcn_mfma_f32_16x16x32_bf16(
            __builtin_bit_cast(bf16x8, a), __builtin_bit_cast(bf16x8, b), c, 0, 0, 0);
    else
        return __builtin_amdgcn_mfma_f32_16x16x32_f16(
            __builtin_bit_cast(f16x8, a), __builtin_bit_cast(f16x8, b), c, 0, 0, 0);
}

// async global->LDS, 16B/lane; LDS dest = wave-uniform base + lane*16.
static __device__ __forceinline__ void gl_lds16(const void* gp, void* lp) {
    auto g1 = (const __attribute__((address_space(1))) uint32_t*)(uintptr_t)gp;
    auto l3 = (__attribute__((address_space(3))) uint32_t*)(uintptr_t)lp;
    __builtin_amdgcn_global_load_lds(g1, l3, 16, 0, 0);
}

template <int N>
static __device__ __forceinline__ void vm_wait() {
    if constexpr (N == 0)      asm volatile("s_waitcnt vmcnt(0)" ::: "memory");
    else if constexpr (N == 2) asm volatile("s_waitcnt vmcnt(2)" ::: "memory");
    else if constexpr (N == 4) asm volatile("s_waitcnt vmcnt(4)" ::: "memory");
    else if constexpr (N == 6) asm volatile("s_waitcnt vmcnt(6)" ::: "memory");
    else if constexpr (N == 8) asm volatile("s_waitcnt vmcnt(8)" ::: "memory");
    else                       static_assert(N == 0, "unsupported vmcnt");
}

// LDS chunk-swizzle fold. CPR=8: row&7 (measured 0-conflict, r7).
// CPR=4: (r ^ r>>2) & 3 -- 2-way per 16-lane phase = free (m136); the plain
// r&3 variant is a 4-way ({0,4,8,12} collide). See r18 header note.
template <int CPR>
static __device__ __forceinline__ int foldf(int r) {
    if constexpr (CPR == 8) return r & 7;
    else                    return (r ^ (r >> 2)) & 3;
}

// flag=1 iff inputs are fp32 (sniff even halfwords of w: fp32 mantissa bits
// look like huge-exponent bf16s; real bf16 |w|<=1 has exp field <= 0x7f).
__global__ void sniff(const uint16_t* __restrict__ wh, int* __restrict__ flag) {
    __shared__ int cnt;
    if (threadIdx.x == 0) cnt = 0;
    __syncthreads();
    int c = 0;
    for (int t = threadIdx.x; t < 4096; t += 256) {
        uint16_t h = wh[(size_t)2 * t * 97];
        c += (((h >> 7) & 0xFF) >= 0x82);
    }
    atomicAdd(&cnt, c);
    __syncthreads();
    if (threadIdx.x == 0) flag[0] = (cnt > 256) ? 1 : 0;
}

__global__ void fill0(int4v* __restrict__ p, long n16) {
    long i = (long)blockIdx.x * 256 + threadIdx.x;
    if (i < n16) p[i] = (int4v){0, 0, 0, 0};
}

static __device__ __forceinline__ float ldin(const void* p, size_t i, int f) {
    return f ? ((const float*)p)[i] : (float)((const bf16_t*)p)[i];
}

// ---- bf16 builders (fallback path) ----
__global__ void build_w(const void* __restrict__ w, bf16_t* __restrict__ wT,
                        bf16_t* __restrict__ wB, const int* __restrict__ flag) {
    const int k = blockIdx.x * 256 + threadIdx.x;
    const int j = blockIdx.y;
    if (k >= 800) return;
    bf16_t v = (bf16_t)0.0f;
    if (k < 784) {
        v = (bf16_t)ldin(w, (size_t)k * 2048 + j, flag[0]);
        wB[(size_t)k * 2048 + j] = v;
    }
    wT[(size_t)j * 800 + k] = v;
}

// ---- f16 builders (G path) ----
__global__ void build_wh(const void* __restrict__ w, f16_t* __restrict__ wTh,
                         const int* __restrict__ flag) {
    const int k = blockIdx.x * 256 + threadIdx.x;   // pixel (pad 800)
    const int j = blockIdx.y;                       // latent
    if (k >= 800) return;
    f16_t v = (f16_t)0.0f;
    if (k < 784) v = (f16_t)ldin(w, (size_t)k * 2048 + j, flag[0]);
    wTh[(size_t)j * 800 + k] = v;
}

__global__ void build_wbh(const void* __restrict__ w, f16_t* __restrict__ wBh,
                          const int* __restrict__ flag) {
    const int j = blockIdx.x * 256 + threadIdx.x;   // latent
    const int p = blockIdx.y;                       // pixel
    if (j >= 2048) return;
    wBh[(size_t)p * 2048 + j] = (f16_t)ldin(w, (size_t)p * 2048 + j, flag[0]);
}

__global__ void build_xh(const void* __restrict__ x, f16_t* __restrict__ xh,
                         const int* __restrict__ flag) {
    const int k = blockIdx.x * 256 + threadIdx.x;   // pixel (pad 800)
    const int i = blockIdx.y;
    if (k >= 800) return;
    f16_t v = (f16_t)0.0f;
    if (k < 784) v = (f16_t)ldin(x, (size_t)i * 784 + k, flag[0]);
    xh[(size_t)i * 800 + k] = v;
}

// NT-GEMM  C[i,j] = sum_k A[i,k]*B[j,k].  Tile BM x BNT, K-step TBK, NW waves
// (wave grid 2 x NW/2; per-wave output 64 x BNT/(NW/2)). Element type ET.
// WEU = launch_bounds min-waves-per-EU (2 -> 256 VGPR budget, 4 -> 128).
// 2-phase double-buffered: stage tile t+1 via global_load_lds while computing
// tile t; counted s_waitcnt vmcnt(L) keeps next tile's loads in flight across
// the barrier. LDS chunk-XOR swizzle (chunk ^= foldf(row), 16B granularity)
// applied on the global source AND the ds_read address (linear LDS dest).
// MODE 0 (R):    r[gm,gn] = x[gm,gn] - C   (gn<N; x dtype per flag) [fallback]
// MODE 1 (STEP): uo=U; ao=relu(uo-.3); un=uo+.01*(C+ao-uo); U=un; a=relu(un-.3)
// MODE 2 (ETOUT):Out[gm,gn] = (ET)C  (gn<N)
// MODE 3 (GSTEP):uo=U; un=uo+0.01*(b - C - uo); U=un; Out=(ET)relu(un-.3)
//                (b at Xin, f32 if BF32 else ET; g has zero diag)
//                per-mt gather epilogue (batched b/u loads, bounded VGPR)
// MODE 4 (F32):  U[gm*ldo+gn] = C
// MODE 5 (GRAM): Out[gm,gn] = (ET)(C - (gm==gn))   -- g = w^T w - I
template <int MODE, bool CLAMPN, int BNT, int TBK, int NW,
          typename ET = bf16_t, bool BF32 = true, int WEU = 4>
__global__ __launch_bounds__(NW * 64, WEU) void gemm_nt(
    const ET* __restrict__ A, const ET* __restrict__ B,
    int N, int K, int lda, int ldb,
    const void* __restrict__ Xin, float* __restrict__ U,
    ET* __restrict__ Out, int ldo, const int* __restrict__ flag)
{
    constexpr int THREADS = NW * 64;
    constexpr int NWN = NW / 2;            // wave-grid cols (2 rows of waves)
    constexpr int MT  = 4;                 // 16-row m-tiles per wave (BM/32)
    constexpr int NTW = BNT / (NWN * 16);  // 16-col n-tiles per wave
    constexpr int CPR = TBK / 8;           // 16B chunks per tile row
    constexpr int AL  = BM * CPR / THREADS;    // A staging insts per thread
    constexpr int BL  = BNT * CPR / THREADS;   // B staging insts per thread
    constexpr int L   = AL + BL;           // loads in flight per tile per wave
    constexpr int KH  = TBK / 32;          // k-halves per tile (MFMA K=32)
    static_assert(AL >= 1 && BL >= 1 && NTW >= 1, "geometry");

    __shared__ __align__(16) ET sA[2][BM * TBK];
    __shared__ __align__(16) ET sB[2][BNT * TBK];

    const int tid  = threadIdx.x;
    const int lane = tid & 63;
    const int wave = tid >> 6;
    const int wm   = wave / NWN;
    const int wn   = wave % NWN;
    const int bm   = blockIdx.x * BM;
    const int bn   = blockIdx.y * BNT;

    f32x4 acc[MT][NTW];
#pragma unroll
    for (int i = 0; i < MT; ++i)
#pragma unroll
        for (int j = 0; j < NTW; ++j) acc[i][j] = (f32x4){0.f, 0.f, 0.f, 0.f};

    // staging map: chunk c = l*THREADS+tid -> LDS row c/CPR, LDS chunk c%CPR,
    // LDS offset c*16B (linear). SOURCE chunk = (c%CPR) ^ foldf(row) so that
    // LDS[row][chunk] holds logical chunk (chunk ^ foldf(row)).
    const ET* gA[AL];
    const ET* gB[BL];
#pragma unroll
    for (int l = 0; l < AL; ++l) {
        const int c  = l * THREADS + tid;
        const int rL = c / CPR;
        const int sc = (c & (CPR - 1)) ^ foldf<CPR>(rL);
        gA[l] = A + (size_t)(bm + rL) * lda + sc * 8;
    }
#pragma unroll
    for (int l = 0; l < BL; ++l) {
        const int c  = l * THREADS + tid;
        const int rL = c / CPR;
        const int sc = (c & (CPR - 1)) ^ foldf<CPR>(rL);
        int rb = bn + rL;
        if (CLAMPN) rb = min(rb, N - 1);
        gB[l] = B + (size_t)rb * ldb + sc * 8;
    }

    auto stage = [&](int buf, int k0) {
#pragma unroll
        for (int l = 0; l < AL; ++l)
            gl_lds16(gA[l] + k0, &sA[buf][(size_t)(l * THREADS + tid) * 8]);
#pragma unroll
        for (int l = 0; l < BL; ++l)
            gl_lds16(gB[l] + k0, &sB[buf][(size_t)(l * THREADS + tid) * 8]);
    };

    const int mrow = lane & 15;
    const int q    = lane >> 4;
    // read-side swizzle: fragment rows are (mult of 16) + mrow; foldf's value
    // on (16t + mrow) equals its value on mrow (16t and 4t vanish mod 4, and
    // for CPR=8 bit3 of 16t+mrow is mrow's... rows are mult-of-16 + mrow with
    // foldf<8> using bits[2:0] of mrow only when 16|base) -> per-lane constant.
    const int swz = foldf<CPR>(mrow);
    const int qx  = q ^ (swz & 3);          // low 2 chunk bits
    const int ksw = swz >> 2;               // chunk bit 2 (CPR=8 only)

    stage(0, 0);
    int cur = 0;
    for (int k0 = 0; k0 < K; k0 += TBK) {
        if (k0 + TBK < K) {
            stage(cur ^ 1, k0 + TBK);   // next tile's DMA in flight across barrier
            vm_wait<L>();               // wait only for CURRENT tile's L loads
        } else {
            vm_wait<0>();               // epilogue drain
        }
        __builtin_amdgcn_s_barrier();   // all waves' DMA for buf[cur] landed
        asm volatile("" ::: "memory");  // don't hoist ds_reads above barrier

        int4v af[MT][KH], bv[NTW][KH];
        const ET* pa = &sA[cur][(wm * 64 + mrow) * TBK + qx * 8];
        const ET* pb = &sB[cur][(wn * (NTW * 16) + mrow) * TBK + qx * 8];
#pragma unroll
        for (int t = 0; t < MT; ++t)
#pragma unroll
            for (int kk = 0; kk < KH; ++kk)
                af[t][kk] = *(const int4v*)(pa + t * 16 * TBK + (kk ^ ksw) * 32);
#pragma unroll
        for (int t = 0; t < NTW; ++t)
#pragma unroll
            for (int kk = 0; kk < KH; ++kk)
                bv[t][kk] = *(const int4v*)(pb + t * 16 * TBK + (kk ^ ksw) * 32);
#pragma unroll
        for (int kk = 0; kk < KH; ++kk)       // logical k-order unchanged
#pragma unroll
            for (int mt = 0; mt < MT; ++mt)
#pragma unroll
                for (int nt = 0; nt < NTW; ++nt)
                    acc[mt][nt] = mfma16<ET>(af[mt][kk], bv[nt][kk], acc[mt][nt]);

        // all our ds_reads must COMPLETE before any wave passes the barrier
        // (next iter's DMA overwrites buf[cur]); MFMA sinking past is harmless.
        asm volatile("s_waitcnt lgkmcnt(0)" ::: "memory");
        __builtin_amdgcn_s_barrier();
        cur ^= 1;
    }

    int f = 0;
    if (MODE == 0) f = flag[0];

    // C/D layout: col = lane&15, row = (lane>>4)*4 + r   [m89/m91]
    const int coln = lane & 15;
    const int rq   = lane >> 4;

    if constexpr (MODE == 3) {
        // per-mt gather-then-compute: batch the 2*4*NTW loads of one m-tile
        // (32 transient VGPR), compute + store, move on. Bounded pressure.
#pragma unroll
        for (int mt = 0; mt < MT; ++mt) {
            float bb[4][NTW], uu[4][NTW];
#pragma unroll
            for (int r = 0; r < 4; ++r) {
                const int gm = bm + wm * 64 + mt * 16 + rq * 4 + r;
#pragma unroll
                for (int nt = 0; nt < NTW; ++nt) {
                    const int gn = bn + wn * (NTW * 16) + nt * 16 + coln;
                    const size_t idx = (size_t)gm * ldo + gn;
                    bb[r][nt] = BF32 ? ((const float*)Xin)[idx]
                                     : (float)((const ET*)Xin)[idx];
                    uu[r][nt] = U[idx];
                }
            }
#pragma unroll
            for (int r = 0; r < 4; ++r) {
                const int gm = bm + wm * 64 + mt * 16 + rq * 4 + r;
#pragma unroll
                for (int nt = 0; nt < NTW; ++nt) {
                    const int gn = bn + wn * (NTW * 16) + nt * 16 + coln;
                    const size_t idx = (size_t)gm * ldo + gn;
                    const float uo = uu[r][nt];
                    const float un = uo + 0.01f * (bb[r][nt] - acc[mt][nt][r] - uo);
                    U[idx] = un;
                    Out[idx] = (ET)fmaxf(un - 0.3f, 0.0f);
                }
            }
        }
        return;
    }

#pragma unroll
    for (int mt = 0; mt < MT; ++mt) {
#pragma unroll
        for (int r = 0; r < 4; ++r) {
            const int gm = bm + wm * 64 + mt * 16 + rq * 4 + r;
#pragma unroll
            for (int nt = 0; nt < NTW; ++nt) {
                const int gn = bn + wn * (NTW * 16) + nt * 16 + coln;
                const float c = acc[mt][nt][r];
                if (MODE == 0) {
                    if (gn < N) {
                        const size_t xi = (size_t)gm * N + gn;
                        const float xv = f ? ((const float*)Xin)[xi]
                                           : (float)((const bf16_t*)Xin)[xi];
                        Out[(size_t)gm * ldo + gn] = (ET)(xv - c);
                    }
                } else if (MODE == 1) {
                    const size_t idx = (size_t)gm * ldo + gn;
                    const float uo = U[idx];
                    const float ao = fmaxf(uo - 0.3f, 0.0f);
                    const float un = uo + 0.01f * (c + ao - uo);
                    U[idx] = un;
                    Out[idx] = (ET)fmaxf(un - 0.3f, 0.0f);
                } else if (MODE == 4) {
                    U[(size_t)gm * ldo + gn] = c;
                } else if (MODE == 5) {
                    Out[(size_t)gm * ldo + gn] = (ET)(gm == gn ? c - 1.0f : c);
                } else {
                    if (gn < N)
                        Out[(size_t)gm * ldo + gn] = (ET)c;
                }
            }
        }
    }
}

// final a: f16 (ws) -> d_out a-region (f32 or bf16 per flag). src in ws, no
// overlap with dst -> single pass.
__global__ void a_out(const f16_t* __restrict__ src, void* __restrict__ dout,
                      const int* __restrict__ flag) {
    long i = (long)blockIdx.x * 256 + threadIdx.x;
    if (i >= 16777216L) return;
    const float v = (float)src[i];
    if (flag[0]) ((float*)dout)[6422528L + i] = v;
    else         ((bf16_t*)dout)[6422528L + i] = (bf16_t)v;
}

// recon: f16 (ws) -> d_out front (f32 or bf16 per flag)
__global__ void recon_out_h(const f16_t* __restrict__ rec, void* __restrict__ dout,
                            const int* __restrict__ flag) {
    long i = (long)blockIdx.x * 256 + threadIdx.x;
    if (i >= 6422528L) return;
    const float v = (float)rec[i];
    if (flag[0]) ((float*)dout)[i] = v;
    else         ((bf16_t*)dout)[i] = (bf16_t)v;
}

// ---- fallback-path epilogue kernels (bf16 residual form) ----
__global__ void a_move(const bf16_t* __restrict__ src, float* __restrict__ dst,
                       long lo, long hi, const int* __restrict__ flag) {
    if (!flag[0]) return;
    long i = lo + (long)blockIdx.x * 256 + threadIdx.x;
    if (i < hi) dst[i] = (float)src[i];
}

__global__ void recon_out(const bf16_t* __restrict__ rec, void* __restrict__ dout,
                          const int* __restrict__ flag) {
    long i = (long)blockIdx.x * 256 + threadIdx.x;
    if (i >= 6422528L) return;
    if (flag[0]) ((float*)dout)[i] = (float)rec[i];
    else         ((bf16_t*)dout)[i] = rec[i];
}

extern "C" void kernel_launch(void* const* d_in, const int* in_sizes, int n_in,
                              void* d_out, int out_size, void* d_ws, size_t ws_size,
                              hipStream_t stream) {
    const void* x = d_in[0];   // [8192, 784]  fp32 or bf16
    const void* w = d_in[1];   // [784, 2048]  fp32 or bf16
    (void)in_sizes; (void)n_in; (void)out_size;

    char* ws = (char*)d_ws;

    if (ws_size >= 145883140UL) {
        // ---------- f16 G-form path (single tier, b in f16) ----------
        float*  u    = (float*)ws;                          // [0, 67.1MB)
        f16_t*  xh   = (f16_t*)ws;                          // aliases u pre-iter
        f16_t*  bH   = (f16_t*)(ws + 67108864);             // 33,554,432
        f16_t*  g    = (f16_t*)(ws + 100663296);            //  8,388,608
        f16_t*  wTh  = (f16_t*)(ws + 109051904);            //  3,276,800
        f16_t*  aP0  = (f16_t*)(ws + 112328704);            // 33,554,432
        int*    flag = (int*)(ws + 145883136);
        f16_t*  aP1  = (f16_t*)d_out;                       // 33.5MB d_out scratch
        f16_t*  wBh  = (f16_t*)ws;                          // aliases u post-loop
        f16_t*  rec  = (f16_t*)(ws + 4194304);              // aliases u post-loop

        sniff<<<1, 256, 0, stream>>>((const uint16_t*)w, flag);
        build_wh<<<dim3(4, 2048), 256, 0, stream>>>(w, wTh, flag);
        build_xh<<<dim3(4, 8192), 256, 0, stream>>>(x, xh, flag);

        // b = xh @ w (f16; xh aliases u -> b-GEMM BEFORE u init)
        gemm_nt<2, false, 128, 32, 4, f16_t><<<dim3(64, 16), 256, 0, stream>>>(
            xh, wTh, 2048, 800, 800, 800, nullptr, nullptr, bH, 2048, flag);
        // g = w^T w - I (f16; diag subtracted in f32 before rounding)
        gemm_nt<5, false, 128, 32, 4, f16_t><<<dim3(16, 16), 256, 0, stream>>>(
            wTh, wTh, 2048, 800, 800, 800, nullptr, nullptr, g, 2048, flag);

        fill0<<<16384, 256, 0, stream>>>((int4v*)u, 4194304L);   // u = 0
        fill0<<<8192, 256, 0, stream>>>((int4v*)aP1, 2097152L);  // a_0 = 0

        // 99 fused steps: C = a@g; u += 0.01*(b - C - u); a = relu(u-0.3)
        // NW=4 2x2 grid (64x64/wave), TBK=32 -> LDS 32KB -> 4 blocks/CU
        // (16 waves/CU) with the corrected free CPR=4 fold; WEU=4 (128 VGPR).
        // ping-pong (WAR-safe across bn-blocks): i reads aP[i&1], writes
        // aP[(i+1)&1]; i=1..99 -> final a in aP0 (ws).
        for (int i = 1; i <= 99; ++i) {
            f16_t* rd = (i & 1) ? aP1 : aP0;
            f16_t* wr = (i & 1) ? aP0 : aP1;
            gemm_nt<3, false, 128, 32, 4, f16_t, false, 4>
                <<<dim3(64, 16), 256, 0, stream>>>(
                rd, g, 2048, 2048, 2048, 2048, bH, u, wr, 2048, flag);
        }

        // u dead: build wBh + rec into u's region; recon = a @ w^T
        build_wbh<<<dim3(8, 784), 256, 0, stream>>>(w, wBh, flag);
        gemm_nt<2, true, 128, 32, 8, f16_t><<<dim3(64, 7), 512, 0, stream>>>(
            aP0, wBh, 784, 2048, 2048, 2048, nullptr, nullptr, rec, 784, flag);

        // outputs (aP1 at d_out dead from here; writes ordered after reads)
        a_out<<<65536, 256, 0, stream>>>(aP0, d_out, flag);
        recon_out_h<<<25088, 256, 0, stream>>>(rec, d_out, flag);
        return;
    }

    // ---------- fallback: round-10 residual path (passed, 9.39 ms) ----------
    float*  u    = (float*)ws;                          // 67,108,864 B
    bf16_t* r    = (bf16_t*)(ws + 67108864);            // 13,107,200 B (8192x800)
    bf16_t* wT   = (bf16_t*)(ws + 80216064);            //  3,276,800 B (2048x800)
    bf16_t* wB   = (bf16_t*)(ws + 83492864);            //  3,211,264 B (784x2048)
    int*    flag = (int*)(ws + 86704128);               // total 86.7 MB
    bf16_t* aA   = (bf16_t*)((char*)d_out + 12845056);  // a scratch
    bf16_t* rec  = r;

    sniff<<<1, 256, 0, stream>>>((const uint16_t*)w, flag);
    fill0<<<16384, 256, 0, stream>>>((int4v*)u, 4194304L);   // u = 0
    fill0<<<3200, 256, 0, stream>>>((int4v*)r, 819200L);     // r = 0 (incl. pad)
    fill0<<<8192, 256, 0, stream>>>((int4v*)aA, 2097152L);   // a = 0
    build_w<<<dim3(4, 2048), 256, 0, stream>>>(w, wT, wB, flag);

    for (int i = 0; i < 99; ++i) {
        gemm_nt<0, true, 128, 32, 8><<<dim3(64, 7), 512, 0, stream>>>(
            aA, wB, 784, 2048, 2048, 2048, x, nullptr, r, 800, flag);
        gemm_nt<1, false, 128, 32, 4><<<dim3(64, 16), 256, 0, stream>>>(
            r, wT, 2048, 800, 800, 800, nullptr, u, aA, 2048, flag);
    }

    gemm_nt<2, true, 128, 32, 8><<<dim3(64, 7), 512, 0, stream>>>(
        aA, wB, 784, 2048, 2048, 2048, nullptr, nullptr, rec, 784, flag);

    float* aOutF = (float*)d_out + 6422528;
    a_move<<<45312, 256, 0, stream>>>(aA, aOutF, 5177344L, 16777216L, flag);
    a_move<<<20224, 256, 0, stream>>>(aA, aOutF, 0L, 5177344L, flag);
    recon_out<<<25088, 256, 0, stream>>>(rec, d_out, flag);
}

// Round 14
// 8554.796 us; speedup vs baseline: 1.1017x; 1.1017x over previous
//
#include <hip/hip_runtime.h>
#include <hip/hip_bf16.h>
#include <stdint.h>

// LCA on MI355X, round 19. G-form f16. Reverts r18 (9.42ms regression) to the
// r17 core (PASSED 8.10ms: MODE 3 TBK=64/NW=4/CPR=8 row&7/WEU=2) and adds
// u-prefetch. r18 lessons: (a) CPR=4 conflicts are FOLD-INDEPENDENT (both
// 2-bit folds = exactly 2^23 cycles) -> only CPR=8+row&7 is conflict-free;
// (b) occupancy 2->4 blk/CU bought nothing (conflict-discounted r18 == r17)
// -> the ~77us/iter is pinned by the ~200MB epilogue burst already running
// at ~6.2TB/s. Fix = overlap, not rate: prefetch the 64 u-values (67MB/iter,
// the largest epilogue load) during the K-loop, 2 loads per kstep issued
// after each kstep's barriers; counted wait becomes vmcnt(10) (8 stage + 2
// eload newest allowed). Static reg indexing via fully unrolled 32-kstep
// MODE-3 loop (K=2048 fixed at call site). Numerics: identical loads and
// k-order -> absmax unchanged (0.015625).
// ws need 145.9MB (proven available); fallback: residual path (9.39ms).

typedef __bf16 bf16_t;
typedef _Float16 f16_t;
typedef float f32x4 __attribute__((ext_vector_type(4)));
typedef __bf16 bf16x8 __attribute__((ext_vector_type(8)));
typedef _Float16 f16x8 __attribute__((ext_vector_type(8)));
typedef int int4v __attribute__((ext_vector_type(4)));

#define BM 128

template <typename ET>
static __device__ __forceinline__ f32x4 mfma16(int4v a, int4v b, f32x4 c) {
    if constexpr (__is_same(ET, bf16_t))
        return __builtin_amdgcn_mfma_f32_16x16x32_bf16(
            __builtin_bit_cast(bf16x8, a), __builtin_bit_cast(bf16x8, b), c, 0, 0, 0);
    else
        return __builtin_amdgcn_mfma_f32_16x16x32_f16(
            __builtin_bit_cast(f16x8, a), __builtin_bit_cast(f16x8, b), c, 0, 0, 0);
}

// async global->LDS, 16B/lane; LDS dest = wave-uniform base + lane*16.
static __device__ __forceinline__ void gl_lds16(const void* gp, void* lp) {
    auto g1 = (const __attribute__((address_space(1))) uint32_t*)(uintptr_t)gp;
    auto l3 = (__attribute__((address_space(3))) uint32_t*)(uintptr_t)lp;
    __builtin_amdgcn_global_load_lds(g1, l3, 16, 0, 0);
}

template <int N>
static __device__ __forceinline__ void vm_wait() {
    if constexpr (N == 0)       asm volatile("s_waitcnt vmcnt(0)" ::: "memory");
    else if constexpr (N == 2)  asm volatile("s_waitcnt vmcnt(2)" ::: "memory");
    else if constexpr (N == 4)  asm volatile("s_waitcnt vmcnt(4)" ::: "memory");
    else if constexpr (N == 6)  asm volatile("s_waitcnt vmcnt(6)" ::: "memory");
    else if constexpr (N == 8)  asm volatile("s_waitcnt vmcnt(8)" ::: "memory");
    else if constexpr (N == 10) asm volatile("s_waitcnt vmcnt(10)" ::: "memory");
    else                        static_assert(N == 0, "unsupported vmcnt");
}

// LDS chunk-swizzle fold. CPR=8: row&7 (measured 0-conflict, r7/r16/r17).
// CPR=4: row&3 -- NOTE r14/r18 measured CPR=4 conflicts (2^23 cycles) are
// IDENTICAL for r&3 and (r^r>>2)&3 -> fold-independent; CPR=4 used only in
// prologue/fallback GEMMs where the cost is negligible.
template <int CPR>
static __device__ __forceinline__ int foldf(int r) {
    if constexpr (CPR == 8) return r & 7;
    else                    return r & 3;
}

// flag=1 iff inputs are fp32 (sniff even halfwords of w: fp32 mantissa bits
// look like huge-exponent bf16s; real bf16 |w|<=1 has exp field <= 0x7f).
__global__ void sniff(const uint16_t* __restrict__ wh, int* __restrict__ flag) {
    __shared__ int cnt;
    if (threadIdx.x == 0) cnt = 0;
    __syncthreads();
    int c = 0;
    for (int t = threadIdx.x; t < 4096; t += 256) {
        uint16_t h = wh[(size_t)2 * t * 97];
        c += (((h >> 7) & 0xFF) >= 0x82);
    }
    atomicAdd(&cnt, c);
    __syncthreads();
    if (threadIdx.x == 0) flag[0] = (cnt > 256) ? 1 : 0;
}

__global__ void fill0(int4v* __restrict__ p, long n16) {
    long i = (long)blockIdx.x * 256 + threadIdx.x;
    if (i < n16) p[i] = (int4v){0, 0, 0, 0};
}

static __device__ __forceinline__ float ldin(const void* p, size_t i, int f) {
    return f ? ((const float*)p)[i] : (float)((const bf16_t*)p)[i];
}

// ---- bf16 builders (fallback path) ----
__global__ void build_w(const void* __restrict__ w, bf16_t* __restrict__ wT,
                        bf16_t* __restrict__ wB, const int* __restrict__ flag) {
    const int k = blockIdx.x * 256 + threadIdx.x;
    const int j = blockIdx.y;
    if (k >= 800) return;
    bf16_t v = (bf16_t)0.0f;
    if (k < 784) {
        v = (bf16_t)ldin(w, (size_t)k * 2048 + j, flag[0]);
        wB[(size_t)k * 2048 + j] = v;
    }
    wT[(size_t)j * 800 + k] = v;
}

// ---- f16 builders (G path) ----
__global__ void build_wh(const void* __restrict__ w, f16_t* __restrict__ wTh,
                         const int* __restrict__ flag) {
    const int k = blockIdx.x * 256 + threadIdx.x;   // pixel (pad 800)
    const int j = blockIdx.y;                       // latent
    if (k >= 800) return;
    f16_t v = (f16_t)0.0f;
    if (k < 784) v = (f16_t)ldin(w, (size_t)k * 2048 + j, flag[0]);
    wTh[(size_t)j * 800 + k] = v;
}

__global__ void build_wbh(const void* __restrict__ w, f16_t* __restrict__ wBh,
                          const int* __restrict__ flag) {
    const int j = blockIdx.x * 256 + threadIdx.x;   // latent
    const int p = blockIdx.y;                       // pixel
    if (j >= 2048) return;
    wBh[(size_t)p * 2048 + j] = (f16_t)ldin(w, (size_t)p * 2048 + j, flag[0]);
}

__global__ void build_xh(const void* __restrict__ x, f16_t* __restrict__ xh,
                         const int* __restrict__ flag) {
    const int k = blockIdx.x * 256 + threadIdx.x;   // pixel (pad 800)
    const int i = blockIdx.y;
    if (k >= 800) return;
    f16_t v = (f16_t)0.0f;
    if (k < 784) v = (f16_t)ldin(x, (size_t)i * 784 + k, flag[0]);
    xh[(size_t)i * 800 + k] = v;
}

// NT-GEMM  C[i,j] = sum_k A[i,k]*B[j,k].  Tile BM x BNT, K-step TBK, NW waves
// (wave grid 2 x NW/2; per-wave output 64 x BNT/(NW/2)). Element type ET.
// WEU = launch_bounds min-waves-per-EU (2 -> 256 VGPR budget, 4 -> 128).
// 2-phase double-buffered: stage tile t+1 via global_load_lds while computing
// tile t; counted s_waitcnt vmcnt(L) keeps next tile's loads in flight across
// the barrier. LDS chunk-XOR swizzle (chunk ^= foldf(row), 16B granularity)
// applied on the global source AND the ds_read address (linear LDS dest).
// MODE 0 (R):    r[gm,gn] = x[gm,gn] - C   (gn<N; x dtype per flag) [fallback]
// MODE 1 (STEP): uo=U; ao=relu(uo-.3); un=uo+.01*(C+ao-uo); U=un; a=relu(un-.3)
// MODE 2 (ETOUT):Out[gm,gn] = (ET)C  (gn<N)
// MODE 3 (GSTEP):uo=U; un=uo+0.01*(b - C - uo); U=un; Out=(ET)relu(un-.3)
//                (b at Xin, f32 if BF32 else ET; g has zero diag)
//                REQUIRES K=2048 (32 unrolled ksteps); u prefetched 2/kstep
//                during the K-loop (counted vmcnt(10)); b gathered in epilogue.
// MODE 4 (F32):  U[gm*ldo+gn] = C
// MODE 5 (GRAM): Out[gm,gn] = (ET)(C - (gm==gn))   -- g = w^T w - I
template <int MODE, bool CLAMPN, int BNT, int TBK, int NW,
          typename ET = bf16_t, bool BF32 = true, int WEU = 4>
__global__ __launch_bounds__(NW * 64, WEU) void gemm_nt(
    const ET* __restrict__ A, const ET* __restrict__ B,
    int N, int K, int lda, int ldb,
    const void* __restrict__ Xin, float* __restrict__ U,
    ET* __restrict__ Out, int ldo, const int* __restrict__ flag)
{
    constexpr int THREADS = NW * 64;
    constexpr int NWN = NW / 2;            // wave-grid cols (2 rows of waves)
    constexpr int MT  = 4;                 // 16-row m-tiles per wave (BM/32)
    constexpr int NTW = BNT / (NWN * 16);  // 16-col n-tiles per wave
    constexpr int CPR = TBK / 8;           // 16B chunks per tile row
    constexpr int AL  = BM * CPR / THREADS;    // A staging insts per thread
    constexpr int BL  = BNT * CPR / THREADS;   // B staging insts per thread
    constexpr int L   = AL + BL;           // loads in flight per tile per wave
    constexpr int KH  = TBK / 32;          // k-halves per tile (MFMA K=32)
    static_assert(AL >= 1 && BL >= 1 && NTW >= 1, "geometry");

    __shared__ __align__(16) ET sA[2][BM * TBK];
    __shared__ __align__(16) ET sB[2][BNT * TBK];

    const int tid  = threadIdx.x;
    const int lane = tid & 63;
    const int wave = tid >> 6;
    const int wm   = wave / NWN;
    const int wn   = wave % NWN;
    const int bm   = blockIdx.x * BM;
    const int bn   = blockIdx.y * BNT;

    f32x4 acc[MT][NTW];
#pragma unroll
    for (int i = 0; i < MT; ++i)
#pragma unroll
        for (int j = 0; j < NTW; ++j) acc[i][j] = (f32x4){0.f, 0.f, 0.f, 0.f};

    // staging map: chunk c = l*THREADS+tid -> LDS row c/CPR, LDS chunk c%CPR,
    // LDS offset c*16B (linear). SOURCE chunk = (c%CPR) ^ foldf(row) so that
    // LDS[row][chunk] holds logical chunk (chunk ^ foldf(row)).
    const ET* gA[AL];
    const ET* gB[BL];
#pragma unroll
    for (int l = 0; l < AL; ++l) {
        const int c  = l * THREADS + tid;
        const int rL = c / CPR;
        const int sc = (c & (CPR - 1)) ^ foldf<CPR>(rL);
        gA[l] = A + (size_t)(bm + rL) * lda + sc * 8;
    }
#pragma unroll
    for (int l = 0; l < BL; ++l) {
        const int c  = l * THREADS + tid;
        const int rL = c / CPR;
        const int sc = (c & (CPR - 1)) ^ foldf<CPR>(rL);
        int rb = bn + rL;
        if (CLAMPN) rb = min(rb, N - 1);
        gB[l] = B + (size_t)rb * ldb + sc * 8;
    }

    auto stage = [&](int buf, int k0) {
#pragma unroll
        for (int l = 0; l < AL; ++l)
            gl_lds16(gA[l] + k0, &sA[buf][(size_t)(l * THREADS + tid) * 8]);
#pragma unroll
        for (int l = 0; l < BL; ++l)
            gl_lds16(gB[l] + k0, &sB[buf][(size_t)(l * THREADS + tid) * 8]);
    };

    const int mrow = lane & 15;
    const int q    = lane >> 4;
    // read-side swizzle: fragment rows are (mult of 16) + mrow, and foldf only
    // uses row bits [2:0] -> per-lane constant.
    const int swz = foldf<CPR>(mrow);
    const int qx  = q ^ (swz & 3);          // low 2 chunk bits
    const int ksw = swz >> 2;               // chunk bit 2 (CPR=8 only)

    // one K-step's ds_reads + MFMAs on buffer `cur` (logical k-order fixed)
    auto compute = [&](int cur) {
        int4v af[MT][KH], bv[NTW][KH];
        const ET* pa = &sA[cur][(wm * 64 + mrow) * TBK + qx * 8];
        const ET* pb = &sB[cur][(wn * (NTW * 16) + mrow) * TBK + qx * 8];
#pragma unroll
        for (int t = 0; t < MT; ++t)
#pragma unroll
            for (int kk = 0; kk < KH; ++kk)
                af[t][kk] = *(const int4v*)(pa + t * 16 * TBK + (kk ^ ksw) * 32);
#pragma unroll
        for (int t = 0; t < NTW; ++t)
#pragma unroll
            for (int kk = 0; kk < KH; ++kk)
                bv[t][kk] = *(const int4v*)(pb + t * 16 * TBK + (kk ^ ksw) * 32);
#pragma unroll
        for (int kk = 0; kk < KH; ++kk)
#pragma unroll
            for (int mt = 0; mt < MT; ++mt)
#pragma unroll
                for (int nt = 0; nt < NTW; ++nt)
                    acc[mt][nt] = mfma16<ET>(af[mt][kk], bv[nt][kk], acc[mt][nt]);
    };

    float uu[MODE == 3 ? 64 : 1];   // MODE 3: prefetched u (static indexing)

    stage(0, 0);

    if constexpr (MODE == 3) {
        // K==2048 guaranteed by call site -> exactly 32 ksteps, fully
        // unrolled so uu[] indices are compile-time constants (rule 20).
        // Per kstep: stage(next, 8 ops) -> vmcnt(10): allow newest
        // {stage_next(8) + eload_prev(2)}, force current tile staged ->
        // barrier -> compute -> lgkmcnt(0)+barrier -> issue 2 u-loads
        // (they fly under the next kstep's MFMA; forced complete at the
        // wait after next -> BW spread, latency hidden).
        const size_t ub = (size_t)(bm + wm * 64 + q * 4) * ldo
                        + (size_t)(bn + wn * 64 + mrow);
        int cur = 0;
#pragma unroll
        for (int j = 0; j < 32; ++j) {
            if (j < 31) {
                stage(cur ^ 1, (j + 1) * TBK);
                if (j == 0) vm_wait<8>();
                else        vm_wait<10>();
            } else {
                vm_wait<0>();
            }
            __builtin_amdgcn_s_barrier();
            asm volatile("" ::: "memory");
            compute(cur);
            asm volatile("s_waitcnt lgkmcnt(0)" ::: "memory");
            __builtin_amdgcn_s_barrier();
            // u-prefetch: e = 2j, 2j+1; e -> (mt=e>>4, r=(e>>2)&3, nt=e&3)
            {
                constexpr int e0s = 0;  // silence unused in odd paths
                (void)e0s;
                const int e0 = 2 * j, e1 = 2 * j + 1;
                uu[e0] = U[ub + (size_t)((e0 >> 4) * 16 + ((e0 >> 2) & 3)) * ldo
                              + (e0 & 3) * 16];
                uu[e1] = U[ub + (size_t)((e1 >> 4) * 16 + ((e1 >> 2) & 3)) * ldo
                              + (e1 & 3) * 16];
            }
            cur ^= 1;
        }
    } else {
        int cur = 0;
        for (int k0 = 0; k0 < K; k0 += TBK) {
            if (k0 + TBK < K) {
                stage(cur ^ 1, k0 + TBK);   // next tile's DMA in flight
                vm_wait<L>();               // wait only CURRENT tile's loads
            } else {
                vm_wait<0>();               // epilogue drain
            }
            __builtin_amdgcn_s_barrier();
            asm volatile("" ::: "memory");
            compute(cur);
            asm volatile("s_waitcnt lgkmcnt(0)" ::: "memory");
            __builtin_amdgcn_s_barrier();
            cur ^= 1;
        }
    }

    int f = 0;
    if (MODE == 0) f = flag[0];

    // C/D layout: col = lane&15, row = (lane>>4)*4 + r   [m89/m91]
    const int coln = lane & 15;
    const int rq   = lane >> 4;

    if constexpr (MODE == 3) {
        // b gather (batched loads), then compute + store using prefetched uu.
        float bb[MT][4][NTW];
#pragma unroll
        for (int mt = 0; mt < MT; ++mt)
#pragma unroll
            for (int r = 0; r < 4; ++r) {
                const int gm = bm + wm * 64 + mt * 16 + rq * 4 + r;
#pragma unroll
                for (int nt = 0; nt < NTW; ++nt) {
                    const int gn = bn + wn * (NTW * 16) + nt * 16 + coln;
                    const size_t idx = (size_t)gm * ldo + gn;
                    bb[mt][r][nt] = BF32 ? ((const float*)Xin)[idx]
                                         : (float)((const ET*)Xin)[idx];
                }
            }
#pragma unroll
        for (int mt = 0; mt < MT; ++mt)
#pragma unroll
            for (int r = 0; r < 4; ++r) {
                const int gm = bm + wm * 64 + mt * 16 + rq * 4 + r;
#pragma unroll
                for (int nt = 0; nt < NTW; ++nt) {
                    const int gn = bn + wn * (NTW * 16) + nt * 16 + coln;
                    const size_t idx = (size_t)gm * ldo + gn;
                    const float uo = uu[mt * 16 + r * 4 + nt];
                    const float un = uo + 0.01f * (bb[mt][r][nt] - acc[mt][nt][r] - uo);
                    U[idx] = un;
                    Out[idx] = (ET)fmaxf(un - 0.3f, 0.0f);
                }
            }
        return;
    }

#pragma unroll
    for (int mt = 0; mt < MT; ++mt) {
#pragma unroll
        for (int r = 0; r < 4; ++r) {
            const int gm = bm + wm * 64 + mt * 16 + rq * 4 + r;
#pragma unroll
            for (int nt = 0; nt < NTW; ++nt) {
                const int gn = bn + wn * (NTW * 16) + nt * 16 + coln;
                const float c = acc[mt][nt][r];
                if (MODE == 0) {
                    if (gn < N) {
                        const size_t xi = (size_t)gm * N + gn;
                        const float xv = f ? ((const float*)Xin)[xi]
                                           : (float)((const bf16_t*)Xin)[xi];
                        Out[(size_t)gm * ldo + gn] = (ET)(xv - c);
                    }
                } else if (MODE == 1) {
                    const size_t idx = (size_t)gm * ldo + gn;
                    const float uo = U[idx];
                    const float ao = fmaxf(uo - 0.3f, 0.0f);
                    const float un = uo + 0.01f * (c + ao - uo);
                    U[idx] = un;
                    Out[idx] = (ET)fmaxf(un - 0.3f, 0.0f);
                } else if (MODE == 4) {
                    U[(size_t)gm * ldo + gn] = c;
                } else if (MODE == 5) {
                    Out[(size_t)gm * ldo + gn] = (ET)(gm == gn ? c - 1.0f : c);
                } else {
                    if (gn < N)
                        Out[(size_t)gm * ldo + gn] = (ET)c;
                }
            }
        }
    }
}

// final a: f16 (ws) -> d_out a-region (f32 or bf16 per flag). src in ws, no
// overlap with dst -> single pass.
__global__ void a_out(const f16_t* __restrict__ src, void* __restrict__ dout,
                      const int* __restrict__ flag) {
    long i = (long)blockIdx.x * 256 + threadIdx.x;
    if (i >= 16777216L) return;
    const float v = (float)src[i];
    if (flag[0]) ((float*)dout)[6422528L + i] = v;
    else         ((bf16_t*)dout)[6422528L + i] = (bf16_t)v;
}

// recon: f16 (ws) -> d_out front (f32 or bf16 per flag)
__global__ void recon_out_h(const f16_t* __restrict__ rec, void* __restrict__ dout,
                            const int* __restrict__ flag) {
    long i = (long)blockIdx.x * 256 + threadIdx.x;
    if (i >= 6422528L) return;
    const float v = (float)rec[i];
    if (flag[0]) ((float*)dout)[i] = v;
    else         ((bf16_t*)dout)[i] = (bf16_t)v;
}

// ---- fallback-path epilogue kernels (bf16 residual form) ----
__global__ void a_move(const bf16_t* __restrict__ src, float* __restrict__ dst,
                       long lo, long hi, const int* __restrict__ flag) {
    if (!flag[0]) return;
    long i = lo + (long)blockIdx.x * 256 + threadIdx.x;
    if (i < hi) dst[i] = (float)src[i];
}

__global__ void recon_out(const bf16_t* __restrict__ rec, void* __restrict__ dout,
                          const int* __restrict__ flag) {
    long i = (long)blockIdx.x * 256 + threadIdx.x;
    if (i >= 6422528L) return;
    if (flag[0]) ((float*)dout)[i] = (float)rec[i];
    else         ((bf16_t*)dout)[i] = rec[i];
}

extern "C" void kernel_launch(void* const* d_in, const int* in_sizes, int n_in,
                              void* d_out, int out_size, void* d_ws, size_t ws_size,
                              hipStream_t stream) {
    const void* x = d_in[0];   // [8192, 784]  fp32 or bf16
    const void* w = d_in[1];   // [784, 2048]  fp32 or bf16
    (void)in_sizes; (void)n_in; (void)out_size;

    char* ws = (char*)d_ws;

    if (ws_size >= 145883140UL) {
        // ---------- f16 G-form path (single tier, b in f16) ----------
        float*  u    = (float*)ws;                          // [0, 67.1MB)
        f16_t*  xh   = (f16_t*)ws;                          // aliases u pre-iter
        f16_t*  bH   = (f16_t*)(ws + 67108864);             // 33,554,432
        f16_t*  g    = (f16_t*)(ws + 100663296);            //  8,388,608
        f16_t*  wTh  = (f16_t*)(ws + 109051904);            //  3,276,800
        f16_t*  aP0  = (f16_t*)(ws + 112328704);            // 33,554,432
        int*    flag = (int*)(ws + 145883136);
        f16_t*  aP1  = (f16_t*)d_out;                       // 33.5MB d_out scratch
        f16_t*  wBh  = (f16_t*)ws;                          // aliases u post-loop
        f16_t*  rec  = (f16_t*)(ws + 4194304);              // aliases u post-loop

        sniff<<<1, 256, 0, stream>>>((const uint16_t*)w, flag);
        build_wh<<<dim3(4, 2048), 256, 0, stream>>>(w, wTh, flag);
        build_xh<<<dim3(4, 8192), 256, 0, stream>>>(x, xh, flag);

        // b = xh @ w (f16; xh aliases u -> b-GEMM BEFORE u init)
        gemm_nt<2, false, 128, 32, 4, f16_t><<<dim3(64, 16), 256, 0, stream>>>(
            xh, wTh, 2048, 800, 800, 800, nullptr, nullptr, bH, 2048, flag);
        // g = w^T w - I (f16; diag subtracted in f32 before rounding)
        gemm_nt<5, false, 128, 32, 4, f16_t><<<dim3(16, 16), 256, 0, stream>>>(
            wTh, wTh, 2048, 800, 800, 800, nullptr, nullptr, g, 2048, flag);

        fill0<<<16384, 256, 0, stream>>>((int4v*)u, 4194304L);   // u = 0
        fill0<<<8192, 256, 0, stream>>>((int4v*)aP1, 2097152L);  // a_0 = 0

        // 99 fused steps: C = a@g; u += 0.01*(b - C - u); a = relu(u-0.3)
        // r17 core: NW=4 2x2 (64x64/wave), TBK=64 (0-conflict CPR=8), WEU=2;
        // + unrolled K-loop with 2-per-kstep u-prefetch (vmcnt(10) counted).
        // ping-pong (WAR-safe across bn-blocks): i reads aP[i&1], writes
        // aP[(i+1)&1]; i=1..99 -> final a in aP0 (ws).
        for (int i = 1; i <= 99; ++i) {
            f16_t* rd = (i & 1) ? aP1 : aP0;
            f16_t* wr = (i & 1) ? aP0 : aP1;
            gemm_nt<3, false, 128, 64, 4, f16_t, false, 2>
                <<<dim3(64, 16), 256, 0, stream>>>(
                rd, g, 2048, 2048, 2048, 2048, bH, u, wr, 2048, flag);
        }

        // u dead: build wBh + rec into u's region; recon = a @ w^T
        build_wbh<<<dim3(8, 784), 256, 0, stream>>>(w, wBh, flag);
        gemm_nt<2, true, 128, 32, 8, f16_t><<<dim3(64, 7), 512, 0, stream>>>(
            aP0, wBh, 784, 2048, 2048, 2048, nullptr, nullptr, rec, 784, flag);

        // outputs (aP1 at d_out dead from here; writes ordered after reads)
        a_out<<<65536, 256, 0, stream>>>(aP0, d_out, flag);
        recon_out_h<<<25088, 256, 0, stream>>>(rec, d_out, flag);
        return;
    }

    // ---------- fallback: round-10 residual path (passed, 9.39 ms) ----------
    float*  u    = (float*)ws;                          // 67,108,864 B
    bf16_t* r    = (bf16_t*)(ws + 67108864);            // 13,107,200 B (8192x800)
    bf16_t* wT   = (bf16_t*)(ws + 80216064);            //  3,276,800 B (2048x800)
    bf16_t* wB   = (bf16_t*)(ws + 83492864);            //  3,211,264 B (784x2048)
    int*    flag = (int*)(ws + 86704128);               // total 86.7 MB
    bf16_t* aA   = (bf16_t*)((char*)d_out + 12845056);  // a scratch
    bf16_t* rec  = r;

    sniff<<<1, 256, 0, stream>>>((const uint16_t*)w, flag);
    fill0<<<16384, 256, 0, stream>>>((int4v*)u, 4194304L);   // u = 0
    fill0<<<3200, 256, 0, stream>>>((int4v*)r, 819200L);     // r = 0 (incl. pad)
    fill0<<<8192, 256, 0, stream>>>((int4v*)aA, 2097152L);   // a = 0
    build_w<<<dim3(4, 2048), 256, 0, stream>>>(w, wT, wB, flag);

    for (int i = 0; i < 99; ++i) {
        gemm_nt<0, true, 128, 32, 8><<<dim3(64, 7), 512, 0, stream>>>(
            aA, wB, 784, 2048, 2048, 2048, x, nullptr, r, 800, flag);
        gemm_nt<1, false, 128, 32, 4><<<dim3(64, 16), 256, 0, stream>>>(
            r, wT, 2048, 800, 800, 800, nullptr, u, aA, 2048, flag);
    }

    gemm_nt<2, true, 128, 32, 8><<<dim3(64, 7), 512, 0, stream>>>(
        aA, wB, 784, 2048, 2048, 2048, nullptr, nullptr, rec, 784, flag);

    float* aOutF = (float*)d_out + 6422528;
    a_move<<<45312, 256, 0, stream>>>(aA, aOutF, 5177344L, 16777216L, flag);
    a_move<<<20224, 256, 0, stream>>>(aA, aOutF, 0L, 5177344L, flag);
    recon_out<<<25088, 256, 0, stream>>>(rec, d_out, flag);
}